// Round 2
// baseline (169.505 us; speedup 1.0000x reference)
//
#include <hip/hip_runtime.h>
#include <math.h>

#define OBS 8
#define ACT 4
#define DIN 12
#define NTRAIN 128
#define BATCH 8
#define NPAIR 36               // triangle a<=c
#define NPT (BATCH*NPAIR)      // 288 pair tasks
#define NGT (BATCH*OBS)        // 64 gp tasks
#define NTASK (NPT+NGT)        // 352

// ws layout (floats)
#define WS_PM  0               // 64   pred_mean[b][e]
#define WS_CC  64              // 768  cross_cov[b][d][e]
#define WS_MN  832             // 512  main[b][a][c]
#define WS_TR  1344            // 64   trace[b][e]
#define WS_CB  1408            // 352  cab (pair) / cnorm (gp), task-indexed
#define WS_W   1760            // 352*144 inverses, task-indexed

// ---------------------------------------------------------------------------
// K1: one thread inverts one 12x12 matrix fully in registers (unrolled
// in-place Gauss-Jordan, no pivoting: matrices are I + PSD-dominated).
// Tasks 0..287: pair (b,a<=c): M = jv + diag(Lam), det(R)=det(M)*prod(isum).
// Tasks 288..351: gp (b,e): B = ivl*jv*ivl + I.
// ---------------------------------------------------------------------------
__global__ void __launch_bounds__(64) k_inv(const float* __restrict__ m_x,
        const float* __restrict__ s_x, const float* __restrict__ s_u,
        const float* __restrict__ c_xu, const float* __restrict__ ls,
        const float* __restrict__ vars, float* __restrict__ ws) {
    int t = blockIdx.x * 64 + threadIdx.x;
    if (t >= NTASK) return;
    bool isPair = t < NPT;
    int b, a = 0, c = 0, e = 0;
    if (isPair) {
        b = t / NPAIR;
        int rem = t % NPAIR;
        while (rem >= OBS - a) { rem -= OBS - a; a++; }
        c = a + rem;
    } else {
        int q = t - NPT; b = q / OBS; e = q % OBS;
    }
    // build joint_var into A (in registers, all indices static)
    float A[DIN][DIN];
    {
        float cxu[OBS][ACT];
        #pragma unroll
        for (int k = 0; k < OBS; k++)
            #pragma unroll
            for (int d = 0; d < ACT; d++) cxu[k][d] = c_xu[(b*OBS+k)*ACT+d];
        #pragma unroll
        for (int r = 0; r < OBS; r++)
            #pragma unroll
            for (int cl = 0; cl < OBS; cl++) A[r][cl] = s_x[(b*OBS+r)*OBS+cl];
        #pragma unroll
        for (int r = 0; r < OBS; r++)
            #pragma unroll
            for (int d = 0; d < ACT; d++) {
                float acc = 0.f;
                #pragma unroll
                for (int k = 0; k < OBS; k++) acc += A[r][k] * cxu[k][d];
                A[r][OBS+d] = acc;
            }
        #pragma unroll
        for (int d = 0; d < ACT; d++)
            #pragma unroll
            for (int r = 0; r < OBS; r++) A[OBS+d][r] = A[r][OBS+d];
        #pragma unroll
        for (int r = 0; r < ACT; r++)
            #pragma unroll
            for (int cl = 0; cl < ACT; cl++) A[OBS+r][OBS+cl] = s_u[(b*ACT+r)*ACT+cl];
    }
    float scale = 1.f;  // extra det factor
    if (isPair) {
        #pragma unroll
        for (int d = 0; d < DIN; d++) {
            float la = ls[a*DIN+d]; la *= la;
            float lc = ls[c*DIN+d]; lc *= lc;
            float is = 1.f/la + 1.f/lc;
            A[d][d] += 1.f/is;      // + Lam_d
            scale *= is;            // det(R) = det(M) * prod(inv_sum)
        }
    } else {
        float il[DIN];
        #pragma unroll
        for (int d = 0; d < DIN; d++) il[d] = 1.f / ls[e*DIN+d];
        #pragma unroll
        for (int r = 0; r < DIN; r++)
            #pragma unroll
            for (int cl = 0; cl < DIN; cl++) A[r][cl] *= il[r]*il[cl];
        #pragma unroll
        for (int d = 0; d < DIN; d++) A[d][d] += 1.f;
    }
    // in-place Gauss-Jordan inversion + det
    float det = 1.f;
    #pragma unroll
    for (int k = 0; k < DIN; k++) {
        float p = A[k][k]; det *= p;
        float ip = 1.f / p;
        #pragma unroll
        for (int j = 0; j < DIN; j++) if (j != k) A[k][j] *= ip;
        #pragma unroll
        for (int r = 0; r < DIN; r++) if (r != k) {
            float f = A[r][k];
            #pragma unroll
            for (int j = 0; j < DIN; j++) if (j != k) A[r][j] -= f * A[k][j];
            A[r][k] = -f * ip;
        }
        A[k][k] = ip;
    }
    float cb = isPair ? (vars[a]*vars[c] / sqrtf(det * scale))
                      : (vars[e] / sqrtf(det));
    ws[WS_CB + t] = cb;
    float* Wp = ws + WS_W + t * 144;
    #pragma unroll
    for (int r = 0; r < DIN; r++)
        #pragma unroll
        for (int cl = 0; cl < DIN; cl++) Wp[r*DIN+cl] = A[r][cl];
}

// ---------------------------------------------------------------------------
// K2: merged sweep. blocks 0..287: pair triangle; 288..351: gp predictive.
// Pair hot loop: s = basei[i] + basej + dot12(h_i, x_j); Q = cab*exp(s).
// ---------------------------------------------------------------------------
__global__ void __launch_bounds__(256) k_main(const float* __restrict__ X,
        const float* __restrict__ ls, const float* __restrict__ m_x,
        const float* __restrict__ m_u, const float* __restrict__ beta,
        const float* __restrict__ invK, float* __restrict__ ws) {
    int blk = blockIdx.x, tid = threadIdx.x;
    __shared__ float Wl[144];
    __shared__ __align__(16) float h[NTRAIN][12];
    __shared__ float basei[NTRAIN], wav[NTRAIN];
    __shared__ float mu[DIN], s_wsum[DIN], s_iscA[DIN], s_qsc[DIN];
    __shared__ float red[4][13];
    if (tid < 144) Wl[tid] = ws[WS_W + blk*144 + tid];
    if (blk < NPT) {
        // ---------------- pair path ----------------
        int b = blk / NPAIR;
        int a = 0, rem = blk % NPAIR;
        while (rem >= OBS - a) { rem -= OBS - a; a++; }
        int c = a + rem;
        bool diag = (a == c);
        if (tid < DIN) {
            float la = ls[a*DIN+tid]; la *= la;
            float lc = ls[c*DIN+tid]; lc *= lc;
            float ia = 1.f/la, ic = 1.f/lc;
            float L = 1.f/(ia+ic);
            s_wsum[tid] = 1.f/(la+lc);
            s_iscA[tid] = L * ia;    // r_i = iscA*x_i - mu
            s_qsc[tid]  = L * ic;    // q_j = qsc*x_j
            mu[tid] = (tid < OBS) ? m_x[b*OBS+tid] : m_u[b*ACT+tid-OBS];
        }
        __syncthreads();
        if (tid < NTRAIN) {
            int i = tid;
            const float4* xr = (const float4*)(X + i*DIN);
            float4 x0 = xr[0], x1 = xr[1], x2 = xr[2];
            float x[12] = {x0.x,x0.y,x0.z,x0.w, x1.x,x1.y,x1.z,x1.w, x2.x,x2.y,x2.z,x2.w};
            float r[12]; float e1 = 0.f;
            #pragma unroll
            for (int d = 0; d < 12; d++) {
                r[d] = s_iscA[d]*x[d] - mu[d];
                e1 += s_wsum[d]*x[d]*x[d];
            }
            float alpha = 0.f;
            #pragma unroll
            for (int d = 0; d < 12; d++) {
                float u = 0.f;
                #pragma unroll
                for (int cl = 0; cl < 12; cl++) u += Wl[d*12+cl]*r[cl];
                alpha += r[d]*u;
                h[i][d] = s_wsum[d]*x[d] - u*s_qsc[d];  // folded cross term
            }
            basei[i] = -0.5f*(e1 + alpha);
            wav[i] = beta[a*NTRAIN+i];
        }
        int j = tid & 127;
        float xj[12], basej, wc;
        {
            const float4* xr = (const float4*)(X + j*DIN);
            float4 x0 = xr[0], x1 = xr[1], x2 = xr[2];
            xj[0]=x0.x; xj[1]=x0.y; xj[2]=x0.z; xj[3]=x0.w;
            xj[4]=x1.x; xj[5]=x1.y; xj[6]=x1.z; xj[7]=x1.w;
            xj[8]=x2.x; xj[9]=x2.y; xj[10]=x2.z; xj[11]=x2.w;
            float q[12]; float e1 = 0.f;
            #pragma unroll
            for (int d = 0; d < 12; d++) {
                q[d] = s_qsc[d]*xj[d];
                e1 += s_wsum[d]*xj[d]*xj[d];
            }
            float bq = 0.f;
            #pragma unroll
            for (int d = 0; d < 12; d++) {
                float u = 0.f;
                #pragma unroll
                for (int cl = 0; cl < 12; cl++) u += Wl[d*12+cl]*q[cl];
                bq += q[d]*u;
            }
            basej = -0.5f*(e1 + bq);
            wc = beta[c*NTRAIN+j];
        }
        __syncthreads();
        float accm = 0.f, acct = 0.f;
        const float* Ka = invK + a*NTRAIN*NTRAIN;
        int ip = tid >> 7;
        #pragma unroll 8
        for (int k = 0; k < 64; k++) {
            int i = ip + 2*k;                       // wave-uniform -> broadcast LDS
            const float4* hp = (const float4*)(&h[i][0]);
            float4 h0 = hp[0], h1 = hp[1], h2 = hp[2];
            float sA = fmaf(h0.x,xj[0], fmaf(h0.y,xj[1], fmaf(h0.z,xj[2], h0.w*xj[3])));
            float sB = fmaf(h1.x,xj[4], fmaf(h1.y,xj[5], fmaf(h1.z,xj[6], h1.w*xj[7])));
            float sC = fmaf(h2.x,xj[8], fmaf(h2.y,xj[9], fmaf(h2.z,xj[10], h2.w*xj[11])));
            float ev = __expf(sA + sB + sC + basei[i] + basej);
            accm = fmaf(wav[i], ev, accm);
            if (diag) acct = fmaf(Ka[i*NTRAIN+j], ev, acct);
        }
        accm *= wc;
        #pragma unroll
        for (int off = 32; off >= 1; off >>= 1) {
            accm += __shfl_xor(accm, off, 64);
            acct += __shfl_xor(acct, off, 64);
        }
        int wv = tid >> 6, lane = tid & 63;
        if (lane == 0) { red[wv][0] = accm; red[wv][1] = acct; }
        __syncthreads();
        if (tid == 0) {
            float cab = ws[WS_CB + blk];
            float m = (red[0][0]+red[1][0]+red[2][0]+red[3][0]) * cab;
            ws[WS_MN + b*64 + a*8 + c] = m;
            ws[WS_MN + b*64 + c*8 + a] = m;          // exact symmetry
            if (diag)
                ws[WS_TR + b*8 + a] = (red[0][1]+red[1][1]+red[2][1]+red[3][1]) * cab;
        }
    } else {
        // ---------------- gp predictive path ----------------
        int q = blk - NPT;
        int b = q / OBS, e = q % OBS;
        if (tid < DIN) {
            s_iscA[tid] = 1.f / ls[e*DIN+tid];       // ivl
            mu[tid] = (tid < OBS) ? m_x[b*OBS+tid] : m_u[b*ACT+tid-OBS];
        }
        __syncthreads();
        float vals[13];
        #pragma unroll
        for (int v = 0; v < 13; v++) vals[v] = 0.f;
        if (tid < NTRAIN) {
            int n = tid;
            const float4* xr = (const float4*)(X + n*DIN);
            float4 x0 = xr[0], x1 = xr[1], x2 = xr[2];
            float x[12] = {x0.x,x0.y,x0.z,x0.w, x1.x,x1.y,x1.z,x1.w, x2.x,x2.y,x2.z,x2.w};
            float iN[12];
            #pragma unroll
            for (int d = 0; d < 12; d++) iN[d] = (x[d]-mu[d]) * s_iscA[d];
            float qq = 0.f; float tv[12];
            #pragma unroll
            for (int d = 0; d < 12; d++) {
                float u = 0.f;
                #pragma unroll
                for (int cl = 0; cl < 12; cl++) u += Wl[d*12+cl]*iN[cl];
                tv[d] = u; qq += iN[d]*u;
            }
            float lb = __expf(-0.5f*qq) * beta[e*NTRAIN+n];
            vals[0] = lb;
            #pragma unroll
            for (int d = 0; d < 12; d++) vals[1+d] = tv[d]*s_iscA[d]*lb;
        }
        #pragma unroll
        for (int v = 0; v < 13; v++)
            #pragma unroll
            for (int off = 32; off >= 1; off >>= 1) vals[v] += __shfl_xor(vals[v], off, 64);
        int wv = tid >> 6, lane = tid & 63;
        if (lane == 0) {
            #pragma unroll
            for (int v = 0; v < 13; v++) red[wv][v] = vals[v];
        }
        __syncthreads();
        if (tid == 0) {
            float cn = ws[WS_CB + blk];
            ws[WS_PM + b*OBS + e] = cn*(red[0][0]+red[1][0]+red[2][0]+red[3][0]);
            for (int d = 0; d < 12; d++)
                ws[WS_CC + (b*DIN+d)*OBS + e] =
                    cn*(red[0][1+d]+red[1][1+d]+red[2][1+d]+red[3][1+d]);
        }
    }
}

// ---------------------------------------------------------------------------
// K3: epilogue. 8 blocks x 64 threads. jv obs-rows recomputed inline.
// ---------------------------------------------------------------------------
__global__ void k_final(const float* __restrict__ m_x, const float* __restrict__ s_x,
                        const float* __restrict__ c_xu, const float* __restrict__ vars,
                        const float* __restrict__ noises, const float* __restrict__ ws,
                        float* __restrict__ out) {
    int b = blockIdx.x, t = threadIdx.x;
    __shared__ float pm[OBS];
    __shared__ float sxs[64];
    const float* cc = ws + WS_CC + b*DIN*OBS;
    const float* mn = ws + WS_MN + b*64;
    const float* tr = ws + WS_TR + b*OBS;
    sxs[t] = s_x[b*64 + t];
    if (t < OBS) {
        float p = ws[WS_PM + b*OBS + t];
        pm[t] = p;
        out[b*OBS + t] = m_x[b*OBS + t] + p;        // m_out
    }
    __syncthreads();
    int r = t >> 3, cl = t & 7;
    float P = mn[r*8 + cl];
    if (r == cl) P += vars[r] - tr[r] + noises[r];
    P -= pm[r]*pm[cl];
    float cxf = 0.f, cxfT = 0.f;
    #pragma unroll
    for (int d = 0; d < 8; d++) {
        cxf  += sxs[r*8+d]  * cc[d*8+cl];
        cxfT += sxs[cl*8+d] * cc[d*8+r];
    }
    #pragma unroll
    for (int d = 0; d < 4; d++) {
        float jr = 0.f, jc = 0.f;
        #pragma unroll
        for (int k = 0; k < 8; k++) {
            float cx = c_xu[(b*OBS+k)*ACT + d];
            jr += sxs[r*8+k]  * cx;
            jc += sxs[cl*8+k] * cx;
        }
        cxf  += jr * cc[(8+d)*8 + cl];
        cxfT += jc * cc[(8+d)*8 + r];
    }
    float S = sxs[r*8+cl] + P + cxf + cxfT;
    if (r == cl) S += 1e-8f;
    out[64 + b*64 + t] = S;                          // s_out
}

// ---------------------------------------------------------------------------
extern "C" void kernel_launch(void* const* d_in, const int* in_sizes, int n_in,
                              void* d_out, int out_size, void* d_ws, size_t ws_size,
                              hipStream_t stream) {
    const float* m_x    = (const float*)d_in[0];
    const float* s_x    = (const float*)d_in[1];
    const float* m_u    = (const float*)d_in[2];
    const float* s_u    = (const float*)d_in[3];
    const float* c_xu   = (const float*)d_in[4];
    const float* X      = (const float*)d_in[5];
    const float* ls     = (const float*)d_in[6];
    const float* vars   = (const float*)d_in[7];
    const float* noises = (const float*)d_in[8];
    const float* invK   = (const float*)d_in[9];
    const float* beta   = (const float*)d_in[10];
    float* out = (float*)d_out;
    float* ws  = (float*)d_ws;

    k_inv<<<(NTASK + 63)/64, 64, 0, stream>>>(m_x, s_x, s_u, c_xu, ls, vars, ws);
    k_main<<<NTASK, 256, 0, stream>>>(X, ls, m_x, m_u, beta, invK, ws);
    k_final<<<BATCH, 64, 0, stream>>>(m_x, s_x, c_xu, vars, noises, ws, out);
}

// Round 3
// 103.451 us; speedup vs baseline: 1.6385x; 1.6385x over previous
//
#include <hip/hip_runtime.h>
#include <math.h>

#define OBS 8
#define ACT 4
#define DIN 12
#define NTRAIN 128
#define BATCH 8
#define NPAIR 36               // triangle a<=c
#define NPT (BATCH*NPAIR)      // 288 pair tasks
#define NGT (BATCH*OBS)        // 64 gp tasks
#define NTASK (NPT+NGT)        // 352

// ws layout (floats)
#define WS_PM  0               // 64   pred_mean[b][e]
#define WS_CC  64              // 768  cross_cov[b][d][e]
#define WS_MN  832             // 512  main[b][a][c]
#define WS_TR  1344            // 64   trace[b][e]

// ---------------------------------------------------------------------------
// Fused kernel: each block builds its own 12x12 matrix, inverts it with a
// wave-parallel shuffle Gauss-Jordan (12 lanes x 12 regs, NO spills), then
// runs its sweep. Blocks 0..287: pair triangle (a<=c); 288..351: gp.
// ---------------------------------------------------------------------------
__global__ void __launch_bounds__(256) k_fused(
    const float* __restrict__ m_x, const float* __restrict__ s_x,
    const float* __restrict__ m_u, const float* __restrict__ s_u,
    const float* __restrict__ c_xu, const float* __restrict__ X,
    const float* __restrict__ ls, const float* __restrict__ vars,
    const float* __restrict__ beta, const float* __restrict__ invK,
    float* __restrict__ ws)
{
    int blk = blockIdx.x, tid = threadIdx.x;
    bool isPair = blk < NPT;
    int b, a = 0, c = 0, e = 0;
    if (isPair) {
        b = blk / NPAIR;
        int rem = blk % NPAIR;
        while (rem >= OBS - a) { rem -= OBS - a; a++; }
        c = a + rem;
    } else {
        int q = blk - NPT; b = q / OBS; e = q % OBS;
    }

    __shared__ float jvs[144];          // joint_var
    __shared__ float Wl[144];           // inverse
    __shared__ float mu[DIN];
    __shared__ float sc_wsum[DIN], sc_iA[DIN], sc_qc[DIN], sc_lam[DIN], sc_isum[DIN];
    __shared__ float s_cab;
    __shared__ __align__(16) float h[NTRAIN][12];
    __shared__ float basei[NTRAIN], wav[NTRAIN];
    __shared__ float red[4][13];

    // ---- stage 0: joint_var + per-dim scalars ----
    if (tid < 144) {
        int r = tid / 12, cl = tid % 12;
        float v;
        if (r < OBS && cl < OBS) {
            v = s_x[(b*OBS+r)*OBS + cl];
        } else if (r < OBS) {
            v = 0.f;
            #pragma unroll
            for (int k = 0; k < OBS; k++)
                v += s_x[(b*OBS+r)*OBS+k] * c_xu[(b*OBS+k)*ACT + (cl-OBS)];
        } else if (cl < OBS) {
            v = 0.f;
            #pragma unroll
            for (int k = 0; k < OBS; k++)
                v += s_x[(b*OBS+cl)*OBS+k] * c_xu[(b*OBS+k)*ACT + (r-OBS)];
        } else {
            v = s_u[(b*ACT+r-OBS)*ACT + (cl-OBS)];
        }
        jvs[tid] = v;
    } else if (tid >= 160 && tid < 172) {
        int d = tid - 160;
        mu[d] = (d < OBS) ? m_x[b*OBS+d] : m_u[b*ACT+d-OBS];
    } else if (tid >= 192 && tid < 204) {
        int d = tid - 192;
        if (isPair) {
            float la = ls[a*DIN+d]; la *= la;
            float lc = ls[c*DIN+d]; lc *= lc;
            float ia = 1.f/la, ic = 1.f/lc;
            float is = ia + ic;
            float L  = 1.f/is;
            sc_wsum[d] = 1.f/(la+lc);
            sc_iA[d] = L*ia;       // r_i = iA*x_i - mu
            sc_qc[d] = L*ic;       // q_j = qc*x_j
            sc_lam[d] = L;
            sc_isum[d] = is;
        } else {
            sc_iA[d] = 1.f / ls[e*DIN+d];   // inv lengthscale
        }
    }
    __syncthreads();

    // ---- stage 1: wave-parallel Gauss-Jordan, lane r owns row r ----
    if (tid < DIN) {
        int r = tid;
        float row[12];
        if (isPair) {
            #pragma unroll
            for (int j = 0; j < 12; j++) row[j] = jvs[r*12+j];
            row[r] += sc_lam[r];                       // M = jv + diag(Lam)
        } else {
            float ir = sc_iA[r];
            #pragma unroll
            for (int j = 0; j < 12; j++) row[j] = ir * sc_iA[j] * jvs[r*12+j];
            row[r] += 1.f;                             // B = il*jv*il + I
        }
        float det = 1.f;
        #pragma unroll
        for (int k = 0; k < 12; k++) {
            float p = __shfl(row[k], k);
            float ip = 1.f / p;
            det *= p;
            float prow[12];
            #pragma unroll
            for (int j = 0; j < 12; j++) prow[j] = __shfl(row[j], k) * ip;
            if (r == k) {
                #pragma unroll
                for (int j = 0; j < 12; j++) row[j] = prow[j];
                row[k] = ip;
            } else {
                float f = row[k];
                #pragma unroll
                for (int j = 0; j < 12; j++) if (j != k) row[j] -= f * prow[j];
                row[k] = -f * ip;
            }
        }
        #pragma unroll
        for (int j = 0; j < 12; j++) Wl[r*12+j] = row[j];
        if (r == 0) {
            if (isPair) {
                float s = det;                          // det(R)=det(M)*prod(isum)
                #pragma unroll
                for (int d = 0; d < 12; d++) s *= sc_isum[d];
                s_cab = vars[a]*vars[c] / sqrtf(s);
            } else {
                s_cab = vars[e] / sqrtf(det);
            }
        }
    }
    __syncthreads();

    // ---- stage 2: sweep ----
    if (isPair) {
        bool diag = (a == c);
        if (tid < NTRAIN) {
            int i = tid;
            const float4* xr = (const float4*)(X + i*DIN);
            float4 x0 = xr[0], x1 = xr[1], x2 = xr[2];
            float x[12] = {x0.x,x0.y,x0.z,x0.w, x1.x,x1.y,x1.z,x1.w, x2.x,x2.y,x2.z,x2.w};
            float r[12]; float e1 = 0.f;
            #pragma unroll
            for (int d = 0; d < 12; d++) {
                r[d] = sc_iA[d]*x[d] - mu[d];
                e1 += sc_wsum[d]*x[d]*x[d];
            }
            float alpha = 0.f;
            #pragma unroll
            for (int d = 0; d < 12; d++) {
                float u = 0.f;
                #pragma unroll
                for (int cl = 0; cl < 12; cl++) u += Wl[d*12+cl]*r[cl];
                alpha += r[d]*u;
                h[i][d] = sc_wsum[d]*x[d] - u*sc_qc[d];   // folded cross term
            }
            basei[i] = -0.5f*(e1 + alpha);
            wav[i] = beta[a*NTRAIN+i];
        }
        int j = tid & 127;
        float xj[12], basej, wc;
        {
            const float4* xr = (const float4*)(X + j*DIN);
            float4 x0 = xr[0], x1 = xr[1], x2 = xr[2];
            xj[0]=x0.x; xj[1]=x0.y; xj[2]=x0.z; xj[3]=x0.w;
            xj[4]=x1.x; xj[5]=x1.y; xj[6]=x1.z; xj[7]=x1.w;
            xj[8]=x2.x; xj[9]=x2.y; xj[10]=x2.z; xj[11]=x2.w;
            float q[12]; float e1 = 0.f;
            #pragma unroll
            for (int d = 0; d < 12; d++) {
                q[d] = sc_qc[d]*xj[d];
                e1 += sc_wsum[d]*xj[d]*xj[d];
            }
            float bq = 0.f;
            #pragma unroll
            for (int d = 0; d < 12; d++) {
                float u = 0.f;
                #pragma unroll
                for (int cl = 0; cl < 12; cl++) u += Wl[d*12+cl]*q[cl];
                bq += q[d]*u;
            }
            basej = -0.5f*(e1 + bq);
            wc = beta[c*NTRAIN+j];
        }
        __syncthreads();
        float accm = 0.f, acct = 0.f;
        const float* Ka = invK + a*NTRAIN*NTRAIN;
        int ip = tid >> 7;
        #pragma unroll 8
        for (int k = 0; k < 64; k++) {
            int i = ip + 2*k;                        // wave-uniform -> LDS broadcast
            const float4* hp = (const float4*)(&h[i][0]);
            float4 h0 = hp[0], h1 = hp[1], h2 = hp[2];
            float sA = fmaf(h0.x,xj[0], fmaf(h0.y,xj[1], fmaf(h0.z,xj[2], h0.w*xj[3])));
            float sB = fmaf(h1.x,xj[4], fmaf(h1.y,xj[5], fmaf(h1.z,xj[6], h1.w*xj[7])));
            float sC = fmaf(h2.x,xj[8], fmaf(h2.y,xj[9], fmaf(h2.z,xj[10], h2.w*xj[11])));
            float ev = __expf(sA + sB + sC + basei[i] + basej);
            accm = fmaf(wav[i], ev, accm);
            if (diag) acct = fmaf(Ka[i*NTRAIN+j], ev, acct);
        }
        accm *= wc;
        #pragma unroll
        for (int off = 32; off >= 1; off >>= 1) {
            accm += __shfl_xor(accm, off, 64);
            acct += __shfl_xor(acct, off, 64);
        }
        int wv = tid >> 6, lane = tid & 63;
        if (lane == 0) { red[wv][0] = accm; red[wv][1] = acct; }
        __syncthreads();
        if (tid == 0) {
            float cab = s_cab;
            float m = (red[0][0]+red[1][0]+red[2][0]+red[3][0]) * cab;
            ws[WS_MN + b*64 + a*8 + c] = m;
            ws[WS_MN + b*64 + c*8 + a] = m;          // exact symmetry
            if (diag)
                ws[WS_TR + b*8 + a] = (red[0][1]+red[1][1]+red[2][1]+red[3][1]) * cab;
        }
    } else {
        // gp predictive path
        float vals[13];
        #pragma unroll
        for (int v = 0; v < 13; v++) vals[v] = 0.f;
        if (tid < NTRAIN) {
            int n = tid;
            const float4* xr = (const float4*)(X + n*DIN);
            float4 x0 = xr[0], x1 = xr[1], x2 = xr[2];
            float x[12] = {x0.x,x0.y,x0.z,x0.w, x1.x,x1.y,x1.z,x1.w, x2.x,x2.y,x2.z,x2.w};
            float iN[12];
            #pragma unroll
            for (int d = 0; d < 12; d++) iN[d] = (x[d]-mu[d]) * sc_iA[d];
            float qq = 0.f; float tv[12];
            #pragma unroll
            for (int d = 0; d < 12; d++) {
                float u = 0.f;
                #pragma unroll
                for (int cl = 0; cl < 12; cl++) u += Wl[d*12+cl]*iN[cl];
                tv[d] = u; qq += iN[d]*u;
            }
            float lb = __expf(-0.5f*qq) * beta[e*NTRAIN+n];
            vals[0] = lb;
            #pragma unroll
            for (int d = 0; d < 12; d++) vals[1+d] = tv[d]*sc_iA[d]*lb;
        }
        #pragma unroll
        for (int v = 0; v < 13; v++)
            #pragma unroll
            for (int off = 32; off >= 1; off >>= 1) vals[v] += __shfl_xor(vals[v], off, 64);
        int wv = tid >> 6, lane = tid & 63;
        if (lane == 0) {
            #pragma unroll
            for (int v = 0; v < 13; v++) red[wv][v] = vals[v];
        }
        __syncthreads();
        if (tid == 0) {
            float cn = s_cab;
            ws[WS_PM + b*OBS + e] = cn*(red[0][0]+red[1][0]+red[2][0]+red[3][0]);
            for (int d = 0; d < 12; d++)
                ws[WS_CC + (b*DIN+d)*OBS + e] =
                    cn*(red[0][1+d]+red[1][1+d]+red[2][1+d]+red[3][1+d]);
        }
    }
}

// ---------------------------------------------------------------------------
// Epilogue. 8 blocks x 64 threads.
// ---------------------------------------------------------------------------
__global__ void k_final(const float* __restrict__ m_x, const float* __restrict__ s_x,
                        const float* __restrict__ c_xu, const float* __restrict__ vars,
                        const float* __restrict__ noises, const float* __restrict__ ws,
                        float* __restrict__ out) {
    int b = blockIdx.x, t = threadIdx.x;
    __shared__ float pm[OBS];
    __shared__ float sxs[64];
    const float* cc = ws + WS_CC + b*DIN*OBS;
    const float* mn = ws + WS_MN + b*64;
    const float* tr = ws + WS_TR + b*OBS;
    sxs[t] = s_x[b*64 + t];
    if (t < OBS) {
        float p = ws[WS_PM + b*OBS + t];
        pm[t] = p;
        out[b*OBS + t] = m_x[b*OBS + t] + p;        // m_out
    }
    __syncthreads();
    int r = t >> 3, cl = t & 7;
    float P = mn[r*8 + cl];
    if (r == cl) P += vars[r] - tr[r] + noises[r];
    P -= pm[r]*pm[cl];
    float cxf = 0.f, cxfT = 0.f;
    #pragma unroll
    for (int d = 0; d < 8; d++) {
        cxf  += sxs[r*8+d]  * cc[d*8+cl];
        cxfT += sxs[cl*8+d] * cc[d*8+r];
    }
    #pragma unroll
    for (int d = 0; d < 4; d++) {
        float jr = 0.f, jc = 0.f;
        #pragma unroll
        for (int k = 0; k < 8; k++) {
            float cx = c_xu[(b*OBS+k)*ACT + d];
            jr += sxs[r*8+k]  * cx;
            jc += sxs[cl*8+k] * cx;
        }
        cxf  += jr * cc[(8+d)*8 + cl];
        cxfT += jc * cc[(8+d)*8 + r];
    }
    float S = sxs[r*8+cl] + P + cxf + cxfT;
    if (r == cl) S += 1e-8f;
    out[64 + b*64 + t] = S;                          // s_out
}

// ---------------------------------------------------------------------------
extern "C" void kernel_launch(void* const* d_in, const int* in_sizes, int n_in,
                              void* d_out, int out_size, void* d_ws, size_t ws_size,
                              hipStream_t stream) {
    const float* m_x    = (const float*)d_in[0];
    const float* s_x    = (const float*)d_in[1];
    const float* m_u    = (const float*)d_in[2];
    const float* s_u    = (const float*)d_in[3];
    const float* c_xu   = (const float*)d_in[4];
    const float* X      = (const float*)d_in[5];
    const float* ls     = (const float*)d_in[6];
    const float* vars   = (const float*)d_in[7];
    const float* noises = (const float*)d_in[8];
    const float* invK   = (const float*)d_in[9];
    const float* beta   = (const float*)d_in[10];
    float* out = (float*)d_out;
    float* ws  = (float*)d_ws;

    k_fused<<<NTASK, 256, 0, stream>>>(m_x, s_x, m_u, s_u, c_xu, X, ls, vars, beta, invK, ws);
    k_final<<<BATCH, 64, 0, stream>>>(m_x, s_x, c_xu, vars, noises, ws, out);
}